// Round 1
// baseline (403.955 us; speedup 1.0000x reference)
//
#include <hip/hip_runtime.h>
#include <hip/hip_bf16.h>
#include <cstdint>

// Problem: N=50000 nodes, E=400000 edges, D=64, H=2.
// Inputs: 0 node_feature[N,64] f32, 1 Wk[2,64,64], 2 bk[2,64], 3 Wq, 4 bq,
//         5 Wv, 6 bv, 7 Wo[64,128], 8 bo[64], 9 src[E] i32, 10 dst[E] i32.
// Output: out_nf[N,64] f32 then edge_weight[E] f32, concatenated.

__device__ __forceinline__ float wave_max_f(float v) {
#pragma unroll
  for (int m = 1; m < 64; m <<= 1) v = fmaxf(v, __shfl_xor(v, m, 64));
  return v;
}
__device__ __forceinline__ float wave_sum_f(float v) {
#pragma unroll
  for (int m = 1; m < 64; m <<= 1) v += __shfl_xor(v, m, 64);
  return v;
}

// ---------------- Kernel 1: per-node K/Q/V projections -------------------
// out[n, h*64+f] = sum_d W[h,f,d] * x[n,d] + b[h,f]
// Thread owns one (h,f) row of W in VGPRs; x is read via wave-uniform
// (readfirstlane) addresses -> scalar loads, broadcast free.
__global__ __launch_bounds__(256) void kqv_kernel(
    const float* __restrict__ nf,
    const float* __restrict__ Wk, const float* __restrict__ bk,
    const float* __restrict__ Wq, const float* __restrict__ bq,
    const float* __restrict__ Wv, const float* __restrict__ bv,
    float* __restrict__ Kout, float* __restrict__ Qout, float* __restrict__ Vout,
    int N) {
  const float* W;
  const float* b;
  float* out;
  if (blockIdx.y == 0) { W = Wk; b = bk; out = Kout; }
  else if (blockIdx.y == 1) { W = Wq; b = bq; out = Qout; }
  else { W = Wv; b = bv; out = Vout; }

  const int tid = threadIdx.x;
  const int hf = tid & 127;   // (h*64+f)
  const int slot = tid >> 7;  // 0 or 1: which of the 2 nodes this block-iter

  float4 wreg[16];
  const float4* wr = (const float4*)(W + (size_t)hf * 64);
#pragma unroll
  for (int j = 0; j < 16; j++) wreg[j] = wr[j];
  const float bb = b[hf];

  for (int n0 = blockIdx.x * 2; n0 < N; n0 += gridDim.x * 2) {
    const int node = n0 + slot;
    if (node >= N) continue;  // N even -> never taken; wave-uniform anyway
    const int nu = __builtin_amdgcn_readfirstlane(node);
    const float4* xr = (const float4*)(nf + (size_t)nu * 64);
    float acc = bb;
#pragma unroll
    for (int j = 0; j < 16; j++) {
      const float4 x = xr[j];
      acc += wreg[j].x * x.x + wreg[j].y * x.y + wreg[j].z * x.z + wreg[j].w * x.w;
    }
    out[(size_t)node * 128 + hf] = acc;
  }
}

// ---------------- Kernel 2: per-edge scores (+ dst degree count) ----------
__global__ __launch_bounds__(256) void score_kernel(
    const float* __restrict__ Kf, const float* __restrict__ Qf,
    const int* __restrict__ src, const int* __restrict__ dst,
    float* __restrict__ score, int* __restrict__ cnt, int E) {
  const int e = blockIdx.x * 256 + threadIdx.x;
  if (e >= E) return;
  const int s = src[e], d = dst[e];
  const float4* kp = (const float4*)(Kf + (size_t)s * 128);
  const float4* qp = (const float4*)(Qf + (size_t)d * 128);
  float s0 = 0.f, s1 = 0.f;
#pragma unroll
  for (int j = 0; j < 16; j++) {
    const float4 a = kp[j], b = qp[j];
    s0 += a.x * b.x + a.y * b.y + a.z * b.z + a.w * b.w;
  }
#pragma unroll
  for (int j = 16; j < 32; j++) {
    const float4 a = kp[j], b = qp[j];
    s1 += a.x * b.x + a.y * b.y + a.z * b.z + a.w * b.w;
  }
  score[2 * (size_t)e] = s0;
  score[2 * (size_t)e + 1] = s1;
  atomicAdd(&cnt[d], 1);
}

// ---------------- CSR build: scan + fill ----------------------------------
__global__ void scan1_kernel(const int* __restrict__ cnt, int* __restrict__ bsum, int N) {
  __shared__ int sd[256];
  const int i = blockIdx.x * 256 + threadIdx.x;
  sd[threadIdx.x] = (i < N) ? cnt[i] : 0;
  __syncthreads();
  for (int ofs = 128; ofs > 0; ofs >>= 1) {
    if (threadIdx.x < ofs) sd[threadIdx.x] += sd[threadIdx.x + ofs];
    __syncthreads();
  }
  if (threadIdx.x == 0) bsum[blockIdx.x] = sd[0];
}

__global__ void scan2_kernel(const int* __restrict__ bsum, int* __restrict__ bofs, int NB) {
  __shared__ int sd[256];
  const int t = threadIdx.x;
  const int orig = (t < NB) ? bsum[t] : 0;
  sd[t] = orig;
  __syncthreads();
  for (int ofs = 1; ofs < 256; ofs <<= 1) {
    const int a = (t >= ofs) ? sd[t - ofs] : 0;
    __syncthreads();
    sd[t] += a;
    __syncthreads();
  }
  if (t < NB) bofs[t] = sd[t] - orig;  // exclusive
}

__global__ void scan3_kernel(const int* __restrict__ cnt, const int* __restrict__ bofs,
                             int* __restrict__ offsets, int N) {
  __shared__ int sd[256];
  const int t = threadIdx.x;
  const int i = blockIdx.x * 256 + t;
  const int v = (i < N) ? cnt[i] : 0;
  sd[t] = v;
  __syncthreads();
  for (int ofs = 1; ofs < 256; ofs <<= 1) {
    const int a = (t >= ofs) ? sd[t - ofs] : 0;
    __syncthreads();
    sd[t] += a;
    __syncthreads();
  }
  if (i < N) offsets[i] = bofs[blockIdx.x] + sd[t] - v;  // exclusive
}

__global__ void fill_kernel(const int* __restrict__ dst, const int* __restrict__ offsets,
                            int* __restrict__ cursor, int* __restrict__ edge_ids, int E) {
  const int e = blockIdx.x * 256 + threadIdx.x;
  if (e >= E) return;
  const int d = dst[e];
  const int pos = offsets[d] + atomicAdd(&cursor[d], 1);
  edge_ids[pos] = e;
}

// ---------------- Kernel 4: per-node segment softmax + weighted V sum -----
// One wave per dst node. Phases 1/2: wave-parallel max & denom over in-edges.
// Phase 3: serial over in-edges, coalesced 256B V-row loads per head.
__global__ __launch_bounds__(256) void node_kernel(
    const float* __restrict__ score, const float* __restrict__ Vf,
    const int* __restrict__ src, const int* __restrict__ offsets,
    const int* __restrict__ cnt, const int* __restrict__ edge_ids,
    float* __restrict__ wv, float* __restrict__ eout, int N) {
  const int lane = threadIdx.x & 63;
  const int wid = threadIdx.x >> 6;
  const int node = blockIdx.x * 4 + wid;
  if (node >= N) return;
  const int off = offsets[node];
  const int deg = cnt[node];

  float m0 = -1e30f, m1 = -1e30f;
  for (int i = lane; i < deg; i += 64) {
    const int e = edge_ids[off + i];
    m0 = fmaxf(m0, score[2 * (size_t)e]);
    m1 = fmaxf(m1, score[2 * (size_t)e + 1]);
  }
  m0 = wave_max_f(m0);
  m1 = wave_max_f(m1);

  float d0 = 0.f, d1 = 0.f;
  for (int i = lane; i < deg; i += 64) {
    const int e = edge_ids[off + i];
    d0 += __expf(score[2 * (size_t)e] - m0);
    d1 += __expf(score[2 * (size_t)e + 1] - m1);
  }
  d0 = wave_sum_f(d0);
  d1 = wave_sum_f(d1);
  const float inv0 = (d0 > 0.f) ? 1.f / d0 : 0.f;
  const float inv1 = (d1 > 0.f) ? 1.f / d1 : 0.f;

  float acc0 = 0.f, acc1 = 0.f;
  for (int i = 0; i < deg; i++) {
    const int e = edge_ids[off + i];  // wave-uniform
    const float w0 = __expf(score[2 * (size_t)e] - m0) * inv0;
    const float w1 = __expf(score[2 * (size_t)e + 1] - m1) * inv1;
    if (lane == 0) eout[e] = 0.5f * (w0 + w1);
    const int s = src[e];
    acc0 += w0 * Vf[(size_t)s * 128 + lane];
    acc1 += w1 * Vf[(size_t)s * 128 + 64 + lane];
  }
  wv[(size_t)node * 128 + lane] = acc0;
  wv[(size_t)node * 128 + 64 + lane] = acc1;
}

// ---------------- Kernel 5: O projection -----------------------------------
// out[n,o] = sum_f wv[n,f] * Wo[o,f] + bo[o].  Wo staged in LDS, stride 129
// (bank-conflict-free), wv rows via wave-uniform scalar loads.
__global__ __launch_bounds__(256) void out_kernel(
    const float* __restrict__ wv, const float* __restrict__ Wo,
    const float* __restrict__ bo, float* __restrict__ out, int N) {
  __shared__ float sWo[64 * 129];
  for (int idx = threadIdx.x; idx < 64 * 128; idx += 256)
    sWo[(idx >> 7) * 129 + (idx & 127)] = Wo[idx];
  __syncthreads();

  const int lane = threadIdx.x & 63;  // output index o
  const int wid = threadIdx.x >> 6;
  const float bb = bo[lane];

  for (int n0 = blockIdx.x * 4 + wid; n0 < N; n0 += gridDim.x * 4) {
    const int nu = __builtin_amdgcn_readfirstlane(n0);
    const float4* xr = (const float4*)(wv + (size_t)nu * 128);
    float acc = bb;
#pragma unroll
    for (int j = 0; j < 32; j++) {
      const float4 x = xr[j];
      const int base = lane * 129 + j * 4;
      acc += sWo[base] * x.x + sWo[base + 1] * x.y + sWo[base + 2] * x.z +
             sWo[base + 3] * x.w;
    }
    out[(size_t)n0 * 64 + lane] = acc;
  }
}

// ---------------- launch ---------------------------------------------------
extern "C" void kernel_launch(void* const* d_in, const int* in_sizes, int n_in,
                              void* d_out, int out_size, void* d_ws, size_t ws_size,
                              hipStream_t stream) {
  const float* nf = (const float*)d_in[0];
  const float* Wk = (const float*)d_in[1];
  const float* bk = (const float*)d_in[2];
  const float* Wq = (const float*)d_in[3];
  const float* bq = (const float*)d_in[4];
  const float* Wv = (const float*)d_in[5];
  const float* bv = (const float*)d_in[6];
  const float* Wo = (const float*)d_in[7];
  const float* bo = (const float*)d_in[8];
  const int* src = (const int*)d_in[9];
  const int* dst = (const int*)d_in[10];

  const int N = in_sizes[0] / 64;
  const int E = in_sizes[9];

  float* out_nf = (float*)d_out;
  float* eout = (float*)d_out + (size_t)N * 64;

  char* w = (char*)d_ws;
  auto alloc = [&](size_t bytes) -> void* {
    void* p = (void*)w;
    w += (bytes + 255) / 256 * 256;
    return p;
  };
  float* K = (float*)alloc((size_t)N * 128 * 4);
  float* Q = (float*)alloc((size_t)N * 128 * 4);
  float* V = (float*)alloc((size_t)N * 128 * 4);
  float* wv = (float*)alloc((size_t)N * 128 * 4);
  float* score = (float*)alloc((size_t)E * 2 * 4);
  int* cnt = (int*)alloc((size_t)N * 4);
  int* cursor = (int*)alloc((size_t)N * 4);
  int* offsets = (int*)alloc((size_t)N * 4);
  int* edge_ids = (int*)alloc((size_t)E * 4);
  int* bsum = (int*)alloc(256 * 4);
  int* bofs = (int*)alloc(256 * 4);

  const int NB = (N + 255) / 256;  // 196 <= 256, fits scan2's one block
  const int EB = (E + 255) / 256;

  hipMemsetAsync(cnt, 0, (size_t)N * 4, stream);
  hipMemsetAsync(cursor, 0, (size_t)N * 4, stream);

  dim3 g1(2048, 3);
  kqv_kernel<<<g1, 256, 0, stream>>>(nf, Wk, bk, Wq, bq, Wv, bv, K, Q, V, N);
  score_kernel<<<EB, 256, 0, stream>>>(K, Q, src, dst, score, cnt, E);
  scan1_kernel<<<NB, 256, 0, stream>>>(cnt, bsum, N);
  scan2_kernel<<<1, 256, 0, stream>>>(bsum, bofs, NB);
  scan3_kernel<<<NB, 256, 0, stream>>>(cnt, bofs, offsets, N);
  fill_kernel<<<EB, 256, 0, stream>>>(dst, offsets, cursor, edge_ids, E);
  node_kernel<<<(N + 3) / 4, 256, 0, stream>>>(score, V, src, offsets, cnt,
                                               edge_ids, wv, eout, N);
  out_kernel<<<1024, 256, 0, stream>>>(wv, Wo, bo, out_nf, N);
}

// Round 2
// 279.539 us; speedup vs baseline: 1.4451x; 1.4451x over previous
//
#include <hip/hip_runtime.h>
#include <hip/hip_bf16.h>
#include <cstdint>

// Problem: N=50000 nodes, E=400000 edges, D=64, H=2.
// Fused design: per-node K/Q(bf16)/V(f32) projections -> CSR by dst ->
// one fused kernel doing score + segment-softmax + weighted-V per node ->
// O projection.

__device__ __forceinline__ float wave_max_f(float v) {
#pragma unroll
  for (int m = 1; m < 64; m <<= 1) v = fmaxf(v, __shfl_xor(v, m, 64));
  return v;
}
__device__ __forceinline__ float wave_sum_f(float v) {
#pragma unroll
  for (int m = 1; m < 64; m <<= 1) v += __shfl_xor(v, m, 64);
  return v;
}

__device__ __forceinline__ unsigned short f2bf(float f) {
  __hip_bfloat16 h = __float2bfloat16(f);
  return *reinterpret_cast<unsigned short*>(&h);
}
// unpack dword of 2 bf16 (little-endian: low half = even element)
__device__ __forceinline__ float2 bf2x(unsigned int u) {
  union { unsigned int i; float f; } a, b;
  a.i = u << 16;
  b.i = u & 0xffff0000u;
  return make_float2(a.f, b.f);
}

// ---------------- Kernel 1: per-node K/Q/V projections -------------------
// K,Q stored bf16 [n][128]; V stored f32 [n][128].
__global__ __launch_bounds__(256) void kqv_kernel(
    const float* __restrict__ nf,
    const float* __restrict__ Wk, const float* __restrict__ bk,
    const float* __restrict__ Wq, const float* __restrict__ bq,
    const float* __restrict__ Wv, const float* __restrict__ bv,
    unsigned short* __restrict__ Kb, unsigned short* __restrict__ Qb,
    float* __restrict__ Vf, int N) {
  const float* W;
  const float* b;
  if (blockIdx.y == 0) { W = Wk; b = bk; }
  else if (blockIdx.y == 1) { W = Wq; b = bq; }
  else { W = Wv; b = bv; }

  const int tid = threadIdx.x;
  const int hf = tid & 127;   // (h*64+f)
  const int slot = tid >> 7;  // 2 nodes per block-iter

  float4 wreg[16];
  const float4* wr = (const float4*)(W + (size_t)hf * 64);
#pragma unroll
  for (int j = 0; j < 16; j++) wreg[j] = wr[j];
  const float bb = b[hf];

  for (int n0 = blockIdx.x * 2; n0 < N; n0 += gridDim.x * 2) {
    const int node = n0 + slot;
    if (node >= N) continue;
    const int nu = __builtin_amdgcn_readfirstlane(node);
    const float4* xr = (const float4*)(nf + (size_t)nu * 64);
    float acc = bb;
#pragma unroll
    for (int j = 0; j < 16; j++) {
      const float4 x = xr[j];
      acc += wreg[j].x * x.x + wreg[j].y * x.y + wreg[j].z * x.z + wreg[j].w * x.w;
    }
    if (blockIdx.y == 0) Kb[(size_t)node * 128 + hf] = f2bf(acc);
    else if (blockIdx.y == 1) Qb[(size_t)node * 128 + hf] = f2bf(acc);
    else Vf[(size_t)node * 128 + hf] = acc;
  }
}

// ---------------- degree count ---------------------------------------------
__global__ __launch_bounds__(256) void count_kernel(const int* __restrict__ dst,
                                                    int* __restrict__ cnt, int E) {
  const int e = blockIdx.x * 256 + threadIdx.x;
  if (e >= E) return;
  atomicAdd(&cnt[dst[e]], 1);
}

// ---------------- CSR build: scan + fill ----------------------------------
__global__ void scan1_kernel(const int* __restrict__ cnt, int* __restrict__ bsum, int N) {
  __shared__ int sd[256];
  const int i = blockIdx.x * 256 + threadIdx.x;
  sd[threadIdx.x] = (i < N) ? cnt[i] : 0;
  __syncthreads();
  for (int ofs = 128; ofs > 0; ofs >>= 1) {
    if (threadIdx.x < ofs) sd[threadIdx.x] += sd[threadIdx.x + ofs];
    __syncthreads();
  }
  if (threadIdx.x == 0) bsum[blockIdx.x] = sd[0];
}

__global__ void scan2_kernel(const int* __restrict__ bsum, int* __restrict__ bofs, int NB) {
  __shared__ int sd[256];
  const int t = threadIdx.x;
  const int orig = (t < NB) ? bsum[t] : 0;
  sd[t] = orig;
  __syncthreads();
  for (int ofs = 1; ofs < 256; ofs <<= 1) {
    const int a = (t >= ofs) ? sd[t - ofs] : 0;
    __syncthreads();
    sd[t] += a;
    __syncthreads();
  }
  if (t < NB) bofs[t] = sd[t] - orig;  // exclusive
}

__global__ void scan3_kernel(const int* __restrict__ cnt, const int* __restrict__ bofs,
                             int* __restrict__ offsets, int N) {
  __shared__ int sd[256];
  const int t = threadIdx.x;
  const int i = blockIdx.x * 256 + t;
  const int v = (i < N) ? cnt[i] : 0;
  sd[t] = v;
  __syncthreads();
  for (int ofs = 1; ofs < 256; ofs <<= 1) {
    const int a = (t >= ofs) ? sd[t - ofs] : 0;
    __syncthreads();
    sd[t] += a;
    __syncthreads();
  }
  if (i < N) offsets[i] = bofs[blockIdx.x] + sd[t] - v;  // exclusive
}

__global__ void fill_kernel(const int* __restrict__ dst, const int* __restrict__ offsets,
                            int* __restrict__ cursor, int* __restrict__ edge_ids, int E) {
  const int e = blockIdx.x * 256 + threadIdx.x;
  if (e >= E) return;
  const int d = dst[e];
  const int pos = offsets[d] + atomicAdd(&cursor[d], 1);
  edge_ids[pos] = e;
}

// ---------------- Fused node kernel ----------------------------------------
// One wave per dst node: scores (wave-parallel dot, coalesced K rows),
// online segment softmax, weighted V accumulation, edge-weight write.
// Lane L owns features 2L,2L+1 (head0 for L<32, head1 for L>=32).
__global__ __launch_bounds__(256) void node_kernel(
    const unsigned short* __restrict__ Kb, const unsigned short* __restrict__ Qb,
    const float* __restrict__ Vf,
    const int* __restrict__ src, const int* __restrict__ offsets,
    const int* __restrict__ cnt, const int* __restrict__ edge_ids,
    float* __restrict__ wv, float* __restrict__ eout, int N) {
  const int lane = threadIdx.x & 63;
  const int wid = threadIdx.x >> 6;
  const int node = blockIdx.x * 4 + wid;
  if (node >= N) return;
  const int off = offsets[node];
  const int deg = cnt[node];

  if (deg == 0) {
    wv[(size_t)node * 128 + 2 * lane] = 0.f;
    wv[(size_t)node * 128 + 2 * lane + 1] = 0.f;
    return;
  }

  const unsigned int qd = ((const unsigned int*)(Qb + (size_t)node * 128))[lane];
  const float2 q = bf2x(qd);

  float m0 = -1e30f, m1 = -1e30f, den0 = 0.f, den1 = 0.f;
  float2 acc = make_float2(0.f, 0.f);

  for (int c0 = 0; c0 < deg; c0 += 64) {
    const int cn = min(64, deg - c0);
    int e_my = 0, s_my = 0;
    if (lane < cn) {
      e_my = edge_ids[off + c0 + lane];
      s_my = src[e_my];
    }
    float sc0 = -1e30f, sc1 = -1e30f;
    for (int i = 0; i < cn; ++i) {
      const int s = __shfl(s_my, i, 64);
      const unsigned int kd = ((const unsigned int*)(Kb + (size_t)s * 128))[lane];
      const float2 k = bf2x(kd);
      float p = k.x * q.x + k.y * q.y;
#pragma unroll
      for (int mm = 1; mm < 32; mm <<= 1) p += __shfl_xor(p, mm, 64);
      const float other = __shfl_xor(p, 32, 64);
      const float s0 = (lane < 32) ? p : other;
      const float s1 = (lane < 32) ? other : p;
      if (lane == i) { sc0 = s0; sc1 = s1; }
    }
    // online rescale with chunk max
    const float cm0 = wave_max_f(sc0);
    const float cm1 = wave_max_f(sc1);
    const float nm0 = fmaxf(m0, cm0), nm1 = fmaxf(m1, cm1);
    const float r0 = __expf(m0 - nm0), r1 = __expf(m1 - nm1);
    den0 *= r0; den1 *= r1;
    const float racc = (lane < 32) ? r0 : r1;
    acc.x *= racc; acc.y *= racc;
    m0 = nm0; m1 = nm1;

    const float w0 = __expf(sc0 - m0);  // lanes >= cn: exp(-1e30) = 0
    const float w1 = __expf(sc1 - m1);
    den0 += wave_sum_f(w0);
    den1 += wave_sum_f(w1);

    for (int i = 0; i < cn; ++i) {
      const float wi0 = __shfl(w0, i, 64);
      const float wi1 = __shfl(w1, i, 64);
      const int s = __shfl(s_my, i, 64);
      const float2 v = ((const float2*)(Vf + (size_t)s * 128))[lane];
      const float wsel = (lane < 32) ? wi0 : wi1;
      acc.x += wsel * v.x;
      acc.y += wsel * v.y;
    }
    if (deg <= 64 && lane < cn) {
      // single chunk: den/m are final here
      eout[e_my] = 0.5f * (w0 / den0 + w1 / den1);
    }
  }

  const float dinv = (lane < 32) ? (1.f / den0) : (1.f / den1);
  wv[(size_t)node * 128 + 2 * lane] = acc.x * dinv;
  wv[(size_t)node * 128 + 2 * lane + 1] = acc.y * dinv;

  if (deg > 64) {
    // rare fallback: recompute scores, write final normalized edge weights
    for (int i = 0; i < deg; ++i) {
      const int e = edge_ids[off + i];
      const int s = e >= 0 ? src[e] : 0;
      const unsigned int kd = ((const unsigned int*)(Kb + (size_t)s * 128))[lane];
      const float2 k = bf2x(kd);
      float p = k.x * q.x + k.y * q.y;
#pragma unroll
      for (int mm = 1; mm < 32; mm <<= 1) p += __shfl_xor(p, mm, 64);
      const float other = __shfl_xor(p, 32, 64);
      const float s0 = (lane < 32) ? p : other;
      const float s1 = (lane < 32) ? other : p;
      if (lane == 0) eout[e] = 0.5f * (__expf(s0 - m0) / den0 + __expf(s1 - m1) / den1);
    }
  }
}

// ---------------- Kernel 5: O projection -----------------------------------
__global__ __launch_bounds__(256) void out_kernel(
    const float* __restrict__ wv, const float* __restrict__ Wo,
    const float* __restrict__ bo, float* __restrict__ out, int N) {
  __shared__ float sWo[64 * 129];
  for (int idx = threadIdx.x; idx < 64 * 128; idx += 256)
    sWo[(idx >> 7) * 129 + (idx & 127)] = Wo[idx];
  __syncthreads();

  const int lane = threadIdx.x & 63;  // output index o
  const int wid = threadIdx.x >> 6;
  const float bb = bo[lane];

  for (int n0 = blockIdx.x * 4 + wid; n0 < N; n0 += gridDim.x * 4) {
    const int nu = __builtin_amdgcn_readfirstlane(n0);
    const float4* xr = (const float4*)(wv + (size_t)nu * 128);
    float acc = bb;
#pragma unroll
    for (int j = 0; j < 32; j++) {
      const float4 x = xr[j];
      const int base = lane * 129 + j * 4;
      acc += sWo[base] * x.x + sWo[base + 1] * x.y + sWo[base + 2] * x.z +
             sWo[base + 3] * x.w;
    }
    out[(size_t)n0 * 64 + lane] = acc;
  }
}

// ---------------- launch ---------------------------------------------------
extern "C" void kernel_launch(void* const* d_in, const int* in_sizes, int n_in,
                              void* d_out, int out_size, void* d_ws, size_t ws_size,
                              hipStream_t stream) {
  const float* nf = (const float*)d_in[0];
  const float* Wk = (const float*)d_in[1];
  const float* bk = (const float*)d_in[2];
  const float* Wq = (const float*)d_in[3];
  const float* bq = (const float*)d_in[4];
  const float* Wv = (const float*)d_in[5];
  const float* bv = (const float*)d_in[6];
  const float* Wo = (const float*)d_in[7];
  const float* bo = (const float*)d_in[8];
  const int* src = (const int*)d_in[9];
  const int* dst = (const int*)d_in[10];

  const int N = in_sizes[0] / 64;
  const int E = in_sizes[9];

  float* out_nf = (float*)d_out;
  float* eout = (float*)d_out + (size_t)N * 64;

  char* w = (char*)d_ws;
  auto alloc = [&](size_t bytes) -> void* {
    void* p = (void*)w;
    w += (bytes + 255) / 256 * 256;
    return p;
  };
  unsigned short* Kb = (unsigned short*)alloc((size_t)N * 128 * 2);
  unsigned short* Qb = (unsigned short*)alloc((size_t)N * 128 * 2);
  float* V = (float*)alloc((size_t)N * 128 * 4);
  float* wv = (float*)alloc((size_t)N * 128 * 4);
  int* cnt = (int*)alloc((size_t)N * 4);
  int* cursor = (int*)alloc((size_t)N * 4);
  int* offsets = (int*)alloc((size_t)N * 4);
  int* edge_ids = (int*)alloc((size_t)E * 4);
  int* bsum = (int*)alloc(256 * 4);
  int* bofs = (int*)alloc(256 * 4);

  const int NB = (N + 255) / 256;  // 196 <= 256 -> scan2 single block ok
  const int EB = (E + 255) / 256;

  hipMemsetAsync(cnt, 0, (size_t)N * 4, stream);
  hipMemsetAsync(cursor, 0, (size_t)N * 4, stream);

  dim3 g1(2048, 3);
  kqv_kernel<<<g1, 256, 0, stream>>>(nf, Wk, bk, Wq, bq, Wv, bv, Kb, Qb, V, N);
  count_kernel<<<EB, 256, 0, stream>>>(dst, cnt, E);
  scan1_kernel<<<NB, 256, 0, stream>>>(cnt, bsum, N);
  scan2_kernel<<<1, 256, 0, stream>>>(bsum, bofs, NB);
  scan3_kernel<<<NB, 256, 0, stream>>>(cnt, bofs, offsets, N);
  fill_kernel<<<EB, 256, 0, stream>>>(dst, offsets, cursor, edge_ids, E);
  node_kernel<<<(N + 3) / 4, 256, 0, stream>>>(Kb, Qb, V, src, offsets, cnt,
                                               edge_ids, wv, eout, N);
  out_kernel<<<1024, 256, 0, stream>>>(wv, Wo, bo, out_nf, N);
}